// Round 1
// baseline (6261.267 us; speedup 1.0000x reference)
//
#include <hip/hip_runtime.h>

#define CHANNELS 32
#define HIDDEN 1024
#define LAYERS 8

// ---------------- degree / init ----------------

__global__ void deg_kernel(const int* __restrict__ src, const int* __restrict__ tgt,
                           int* __restrict__ deg_in, int* __restrict__ deg_out, int n_edges) {
    int e = blockIdx.x * blockDim.x + threadIdx.x;
    if (e < n_edges) {
        atomicAdd(&deg_in[tgt[e]], 1);
        atomicAdd(&deg_out[src[e]], 1);
    }
}

__global__ void init_kernel(const int* __restrict__ nodes, const int* __restrict__ batch,
                            const float* __restrict__ emb,
                            const int* __restrict__ deg_in, const int* __restrict__ deg_out,
                            float* __restrict__ x, float* __restrict__ norm,
                            float* __restrict__ norm_t, float* __restrict__ counts, int n_nodes) {
    int gid = blockIdx.x * blockDim.x + threadIdx.x;
    int i = gid >> 5, c = gid & 31;
    if (i >= n_nodes) return;
    x[gid] = emb[nodes[i] * CHANNELS + c];
    if (c == 0) {
        norm[i]   = 1.0f / (1.0f + (float)deg_in[i]);
        norm_t[i] = 1.0f / (1.0f + (float)deg_out[i]);
        atomicAdd(&counts[batch[i]], 1.0f);
    }
}

// ---------------- per-layer edge scatter (both directions fused) ----------------

__global__ __launch_bounds__(256)
void edge_kernel(const int* __restrict__ src, const int* __restrict__ tgt,
                 const float* __restrict__ x,
                 float* __restrict__ aggA, float* __restrict__ aggB, int n_edges) {
    int gid = blockIdx.x * blockDim.x + threadIdx.x;   // n_edges*32 < 2^31
    int e = gid >> 5, c = gid & 31;
    if (e >= n_edges) return;
    int s = src[e], t = tgt[e];
    float xs = x[s * CHANNELS + c];
    float xt = x[t * CHANNELS + c];
    atomicAdd(&aggA[t * CHANNELS + c], xs);   // segment_sum(x[s], t)
    atomicAdd(&aggB[s * CHANNELS + c], xt);   // segment_sum(x[t], s)
}

// ---------------- per-layer node update: x += relu(a1@w0) + relu(a2@w1) ----------------

__global__ __launch_bounds__(256)
void node_kernel(const float* __restrict__ conv_w, int layer,
                 const float* __restrict__ norm, const float* __restrict__ norm_t,
                 float* __restrict__ x, float* __restrict__ aggA, float* __restrict__ aggB,
                 int n_nodes) {
    __shared__ float w0[CHANNELS][CHANNELS];
    __shared__ float w1[CHANNELS][CHANNELS];
    int tid = threadIdx.x;
    const float* wbase = conv_w + (size_t)layer * 2 * CHANNELS * CHANNELS;
    for (int idx = tid; idx < CHANNELS * CHANNELS; idx += blockDim.x) {
        w0[idx >> 5][idx & 31] = wbase[idx];
        w1[idx >> 5][idx & 31] = wbase[CHANNELS * CHANNELS + idx];
    }
    __syncthreads();
    int gid = blockIdx.x * blockDim.x + tid;
    int i = gid >> 5, c = gid & 31;
    if (i >= n_nodes) return;
    float xv = x[gid];
    float a1 = norm[i]   * (xv + aggA[gid]);
    float a2 = norm_t[i] * (xv + aggB[gid]);
    aggA[gid] = 0.0f;   // re-zero for next layer
    aggB[gid] = 0.0f;
    float y1 = 0.f, y2 = 0.f;
#pragma unroll
    for (int k = 0; k < CHANNELS; k++) {
        float a1k = __shfl(a1, k, 32);
        float a2k = __shfl(a2, k, 32);
        y1 += a1k * w0[k][c];
        y2 += a2k * w1[k][c];
    }
    x[gid] = xv + fmaxf(y1, 0.f) + fmaxf(y2, 0.f);
}

// ---------------- pooling: run-length accumulate over sorted batch ----------------

#define POOL_CHUNK 2048

__global__ __launch_bounds__(256)
void pool_kernel(const int* __restrict__ batch, const float* __restrict__ x,
                 float* __restrict__ g, int n_nodes) {
    int c = threadIdx.x & 31;
    int r = threadIdx.x >> 5;          // 0..7
    int base = blockIdx.x * POOL_CHUNK;
    float acc = 0.f;
    int cur = -1;
    for (int it = 0; it < POOL_CHUNK / 8; it++) {
        int node = base + it * 8 + r;
        if (node >= n_nodes) break;
        int b = batch[node];
        if (b != cur) {
            if (cur >= 0) atomicAdd(&g[cur * CHANNELS + c], acc);
            acc = 0.f;
            cur = b;
        }
        acc += x[node * CHANNELS + c];
    }
    if (cur >= 0) atomicAdd(&g[cur * CHANNELS + c], acc);
}

// ---------------- MLP head: one block per graph ----------------

__global__ __launch_bounds__(256)
void mlp_kernel(const float* __restrict__ g, const float* __restrict__ counts,
                const float* __restrict__ hidden_w, const float* __restrict__ hidden_b,
                const float* __restrict__ out_w, float* __restrict__ out) {
    __shared__ float grow[CHANNELS];
    __shared__ float red[256];
    int graph = blockIdx.x;
    int tid = threadIdx.x;
    if (tid < CHANNELS) grow[tid] = g[graph * CHANNELS + tid] / counts[graph];
    __syncthreads();
    float partial = 0.f;
    for (int q = 0; q < HIDDEN / 256; q++) {
        int j = q * 256 + tid;
        float h = hidden_b[j];
#pragma unroll
        for (int k = 0; k < CHANNELS; k++) h += grow[k] * hidden_w[k * HIDDEN + j];
        partial += fmaxf(h, 0.f) * out_w[j];
    }
    red[tid] = partial;
    __syncthreads();
    for (int s = 128; s > 0; s >>= 1) {
        if (tid < s) red[tid] += red[tid + s];
        __syncthreads();
    }
    if (tid == 0) out[graph] = red[0];
}

// ---------------- launch ----------------

extern "C" void kernel_launch(void* const* d_in, const int* in_sizes, int n_in,
                              void* d_out, int out_size, void* d_ws, size_t ws_size,
                              hipStream_t stream) {
    const int*   nodes    = (const int*)d_in[0];
    const int*   sources  = (const int*)d_in[1];
    const int*   targets  = (const int*)d_in[2];
    const int*   batch    = (const int*)d_in[3];
    const float* emb      = (const float*)d_in[4];
    const float* conv_w   = (const float*)d_in[5];
    const float* hidden_w = (const float*)d_in[6];
    const float* hidden_b = (const float*)d_in[7];
    const float* out_w    = (const float*)d_in[8];
    float* out = (float*)d_out;

    const int n_nodes  = in_sizes[0];
    const int n_edges  = in_sizes[1];
    const int n_graphs = out_size;

    char* ws = (char*)d_ws;
    float* x      = (float*)ws; ws += (size_t)n_nodes * CHANNELS * 4;
    float* aggA   = (float*)ws; ws += (size_t)n_nodes * CHANNELS * 4;
    float* aggB   = (float*)ws; ws += (size_t)n_nodes * CHANNELS * 4;
    float* norm   = (float*)ws; ws += (size_t)n_nodes * 4;
    float* norm_t = (float*)ws; ws += (size_t)n_nodes * 4;
    int*   deg_in = (int*)ws;   ws += (size_t)n_nodes * 4;
    int*   deg_out= (int*)ws;   ws += (size_t)n_nodes * 4;
    float* g      = (float*)ws; ws += (size_t)n_graphs * CHANNELS * 4;
    float* counts = (float*)ws; ws += (size_t)n_graphs * 4;

    // zero the accumulators (aggA,aggB contiguous; deg_in,deg_out contiguous; g,counts contiguous)
    hipMemsetAsync(aggA, 0, (size_t)n_nodes * CHANNELS * 4 * 2, stream);
    hipMemsetAsync(deg_in, 0, (size_t)n_nodes * 4 * 2, stream);
    hipMemsetAsync(g, 0, (size_t)n_graphs * (CHANNELS + 1) * 4, stream);

    deg_kernel<<<(n_edges + 255) / 256, 256, 0, stream>>>(sources, targets, deg_in, deg_out, n_edges);

    int node_thr = n_nodes * CHANNELS;
    init_kernel<<<(node_thr + 255) / 256, 256, 0, stream>>>(nodes, batch, emb, deg_in, deg_out,
                                                            x, norm, norm_t, counts, n_nodes);

    int edge_thr = n_edges * CHANNELS;
    for (int l = 0; l < LAYERS; l++) {
        edge_kernel<<<(edge_thr + 255) / 256, 256, 0, stream>>>(sources, targets, x, aggA, aggB, n_edges);
        node_kernel<<<(node_thr + 255) / 256, 256, 0, stream>>>(conv_w, l, norm, norm_t,
                                                                x, aggA, aggB, n_nodes);
    }

    int pool_blocks = (n_nodes + POOL_CHUNK - 1) / POOL_CHUNK;
    pool_kernel<<<pool_blocks, 256, 0, stream>>>(batch, x, g, n_nodes);

    mlp_kernel<<<n_graphs, 256, 0, stream>>>(g, counts, hidden_w, hidden_b, out_w, out);
}

// Round 2
// 3266.139 us; speedup vs baseline: 1.9170x; 1.9170x over previous
//
#include <hip/hip_runtime.h>

#define CHANNELS 32
#define HIDDEN 1024
#define LAYERS 8

// ---------------- degree count (int atomics, once) ----------------

__global__ void deg_kernel(const int* __restrict__ src, const int* __restrict__ tgt,
                           int* __restrict__ deg2, int n_nodes, int n_edges) {
    int e = blockIdx.x * blockDim.x + threadIdx.x;
    if (e < n_edges) {
        atomicAdd(&deg2[tgt[e]], 1);            // in-degree
        atomicAdd(&deg2[n_nodes + src[e]], 1);  // out-degree
    }
}

// ---------------- 3-kernel exclusive prefix scan over deg2[0..n2) ----------------

__global__ __launch_bounds__(256)
void scan_pass1(const int* __restrict__ deg, int* __restrict__ bs, int n) {
    __shared__ int sh[256];
    int t = threadIdx.x;
    int base = blockIdx.x * 2048 + t * 8;
    int s = 0;
#pragma unroll
    for (int j = 0; j < 8; j++) { int idx = base + j; if (idx < n) s += deg[idx]; }
    sh[t] = s; __syncthreads();
    for (int st = 128; st > 0; st >>= 1) { if (t < st) sh[t] += sh[t + st]; __syncthreads(); }
    if (t == 0) bs[blockIdx.x] = sh[0];
}

__global__ void scan_pass2(int* __restrict__ bs, int nb) {
    __shared__ int sh[1024];
    int t = threadIdx.x;
    int v = (t < nb) ? bs[t] : 0;
    sh[t] = v; __syncthreads();
    for (int off = 1; off < 1024; off <<= 1) {
        int u = (t >= off) ? sh[t - off] : 0; __syncthreads();
        sh[t] += u; __syncthreads();
    }
    if (t < nb) bs[t] = sh[t] - v;   // exclusive
}

__global__ __launch_bounds__(256)
void scan_pass3(const int* __restrict__ deg, const int* __restrict__ bs,
                int* __restrict__ off, int n) {
    __shared__ int sh[256];
    int t = threadIdx.x;
    int base = blockIdx.x * 2048 + t * 8;
    int v[8]; int s = 0;
#pragma unroll
    for (int j = 0; j < 8; j++) { int idx = base + j; v[j] = (idx < n) ? deg[idx] : 0; s += v[j]; }
    sh[t] = s; __syncthreads();
    for (int st = 1; st < 256; st <<= 1) {
        int u = (t >= st) ? sh[t - st] : 0; __syncthreads();
        sh[t] += u; __syncthreads();
    }
    int acc = bs[blockIdx.x] + sh[t] - s;   // exclusive base for this thread
#pragma unroll
    for (int j = 0; j < 8; j++) { int idx = base + j; if (idx < n) off[idx] = acc; acc += v[j]; }
}

// ---------------- scatter edges into neighbor lists (int atomics, once) ----------------

__global__ __launch_bounds__(256)
void scatter_kernel(const int* __restrict__ src, const int* __restrict__ tgt,
                    int* __restrict__ cur2, int* __restrict__ nbr,
                    int n_nodes, int n_edges) {
    int e = blockIdx.x * blockDim.x + threadIdx.x;
    if (e >= n_edges) return;
    int s = src[e], t = tgt[e];
    int p = atomicAdd(&cur2[t], 1);            nbr[p] = s;   // in-neighbors of t
    int q = atomicAdd(&cur2[n_nodes + s], 1);  nbr[q] = t;   // out-neighbors of s
}

// ---------------- init: x = emb[nodes], norms from degrees ----------------

__global__ __launch_bounds__(256)
void init_kernel(const int* __restrict__ nodes, const float* __restrict__ emb,
                 const int* __restrict__ deg2,
                 float* __restrict__ x, float* __restrict__ norm,
                 float* __restrict__ norm_t, int n_nodes) {
    int gid = blockIdx.x * blockDim.x + threadIdx.x;
    int i = gid >> 5, c = gid & 31;
    if (i >= n_nodes) return;
    x[gid] = emb[nodes[i] * CHANNELS + c];
    if (c == 0) {
        norm[i]   = 1.0f / (1.0f + (float)deg2[i]);
        norm_t[i] = 1.0f / (1.0f + (float)deg2[n_nodes + i]);
    }
}

// ---------------- counts via binary search over sorted batch ----------------

__global__ void counts_kernel(const int* __restrict__ batch, float* __restrict__ counts,
                              int n_nodes, int n_graphs) {
    int b = blockIdx.x * blockDim.x + threadIdx.x;
    if (b >= n_graphs) return;
    int lo = 0, hi = n_nodes;
    while (lo < hi) { int mid = (lo + hi) >> 1; if (batch[mid] < b) lo = mid + 1; else hi = mid; }
    int s = lo;
    lo = 0; hi = n_nodes;
    while (lo < hi) { int mid = (lo + hi) >> 1; if (batch[mid] < b + 1) lo = mid + 1; else hi = mid; }
    counts[b] = (float)(lo - s);
}

// ---------------- fused layer: gather both directions + matvecs + residual ----------------

__global__ __launch_bounds__(256)
void layer_kernel(const int* __restrict__ off2, const int* __restrict__ nbr,
                  const float* __restrict__ wbase,
                  const float* __restrict__ norm, const float* __restrict__ norm_t,
                  const float* __restrict__ xin, float* __restrict__ xout,
                  int n_nodes, int n_edges) {
    __shared__ float w0[CHANNELS][CHANNELS];
    __shared__ float w1[CHANNELS][CHANNELS];
    int tid = threadIdx.x;
    for (int idx = tid; idx < CHANNELS * CHANNELS; idx += 256) {
        w0[idx >> 5][idx & 31] = wbase[idx];
        w1[idx >> 5][idx & 31] = wbase[CHANNELS * CHANNELS + idx];
    }
    __syncthreads();
    int gid = blockIdx.x * 256 + tid;
    int i = gid >> 5, c = gid & 31;
    if (i >= n_nodes) return;

    float xv = xin[gid];

    int b_in  = off2[i];
    int e_in  = (i + 1 < n_nodes) ? off2[i + 1] : n_edges;
    int b_out = off2[n_nodes + i];
    int e_out = (i + 1 < n_nodes) ? off2[n_nodes + i + 1] : 2 * n_edges;

    // in-direction aggregation: preload up to 32 neighbor ids, broadcast via shfl
    float a1 = 0.f;
    {
        int deg = e_in - b_in;
        int nbl = (c < deg) ? nbr[b_in + c] : 0;
        int m = deg < 32 ? deg : 32;
        for (int j = 0; j < m; j++) {
            int nb = __shfl(nbl, j, 32);
            a1 += xin[nb * CHANNELS + c];
        }
        for (int e = b_in + 32; e < e_in; e++) a1 += xin[nbr[e] * CHANNELS + c];
    }
    float a2 = 0.f;
    {
        int deg = e_out - b_out;
        int nbl = (c < deg) ? nbr[b_out + c] : 0;
        int m = deg < 32 ? deg : 32;
        for (int j = 0; j < m; j++) {
            int nb = __shfl(nbl, j, 32);
            a2 += xin[nb * CHANNELS + c];
        }
        for (int e = b_out + 32; e < e_out; e++) a2 += xin[nbr[e] * CHANNELS + c];
    }

    a1 = norm[i]   * (xv + a1);
    a2 = norm_t[i] * (xv + a2);

    float y1 = 0.f, y2 = 0.f;
#pragma unroll
    for (int k = 0; k < CHANNELS; k++) {
        float a1k = __shfl(a1, k, 32);
        float a2k = __shfl(a2, k, 32);
        y1 += a1k * w0[k][c];
        y2 += a2k * w1[k][c];
    }
    xout[gid] = xv + fmaxf(y1, 0.f) + fmaxf(y2, 0.f);
}

// ---------------- pooling: run-length accumulate over sorted batch ----------------

#define POOL_CHUNK 2048

__global__ __launch_bounds__(256)
void pool_kernel(const int* __restrict__ batch, const float* __restrict__ x,
                 float* __restrict__ g, int n_nodes) {
    int c = threadIdx.x & 31;
    int r = threadIdx.x >> 5;          // 0..7
    int base = blockIdx.x * POOL_CHUNK;
    float acc = 0.f;
    int cur = -1;
    for (int it = 0; it < POOL_CHUNK / 8; it++) {
        int node = base + it * 8 + r;
        if (node >= n_nodes) break;
        int b = batch[node];
        if (b != cur) {
            if (cur >= 0) atomicAdd(&g[cur * CHANNELS + c], acc);
            acc = 0.f;
            cur = b;
        }
        acc += x[node * CHANNELS + c];
    }
    if (cur >= 0) atomicAdd(&g[cur * CHANNELS + c], acc);
}

// ---------------- MLP head: one block per graph ----------------

__global__ __launch_bounds__(256)
void mlp_kernel(const float* __restrict__ g, const float* __restrict__ counts,
                const float* __restrict__ hidden_w, const float* __restrict__ hidden_b,
                const float* __restrict__ out_w, float* __restrict__ out) {
    __shared__ float grow[CHANNELS];
    __shared__ float red[256];
    int graph = blockIdx.x;
    int tid = threadIdx.x;
    if (tid < CHANNELS) grow[tid] = g[graph * CHANNELS + tid] / counts[graph];
    __syncthreads();
    float partial = 0.f;
    for (int q = 0; q < HIDDEN / 256; q++) {
        int j = q * 256 + tid;
        float h = hidden_b[j];
#pragma unroll
        for (int k = 0; k < CHANNELS; k++) h += grow[k] * hidden_w[k * HIDDEN + j];
        partial += fmaxf(h, 0.f) * out_w[j];
    }
    red[tid] = partial;
    __syncthreads();
    for (int s = 128; s > 0; s >>= 1) {
        if (tid < s) red[tid] += red[tid + s];
        __syncthreads();
    }
    if (tid == 0) out[graph] = red[0];
}

// ---------------- launch ----------------

extern "C" void kernel_launch(void* const* d_in, const int* in_sizes, int n_in,
                              void* d_out, int out_size, void* d_ws, size_t ws_size,
                              hipStream_t stream) {
    const int*   nodes    = (const int*)d_in[0];
    const int*   sources  = (const int*)d_in[1];
    const int*   targets  = (const int*)d_in[2];
    const int*   batch    = (const int*)d_in[3];
    const float* emb      = (const float*)d_in[4];
    const float* conv_w   = (const float*)d_in[5];
    const float* hidden_w = (const float*)d_in[6];
    const float* hidden_b = (const float*)d_in[7];
    const float* out_w    = (const float*)d_in[8];
    float* out = (float*)d_out;

    const int n_nodes  = in_sizes[0];
    const int n_edges  = in_sizes[1];
    const int n_graphs = out_size;
    const int n2 = 2 * n_nodes;

    char* ws = (char*)d_ws;
    float* x0     = (float*)ws; ws += (size_t)n_nodes * CHANNELS * 4;
    float* x1     = (float*)ws; ws += (size_t)n_nodes * CHANNELS * 4;
    float* norm   = (float*)ws; ws += (size_t)n_nodes * 4;
    float* norm_t = (float*)ws; ws += (size_t)n_nodes * 4;
    int*   deg2   = (int*)ws;   ws += (size_t)n2 * 4;
    int*   off2   = (int*)ws;   ws += (size_t)n2 * 4;
    int*   cur2   = (int*)ws;   ws += (size_t)n2 * 4;
    int*   nbr    = (int*)ws;   ws += (size_t)2 * n_edges * 4;
    int*   bsums  = (int*)ws;   ws += 4096;
    float* g      = (float*)ws; ws += (size_t)n_graphs * CHANNELS * 4;
    float* counts = (float*)ws; ws += (size_t)n_graphs * 4;

    hipMemsetAsync(deg2, 0, (size_t)n2 * 4, stream);
    hipMemsetAsync(g, 0, (size_t)n_graphs * CHANNELS * 4, stream);

    // 1. degrees
    deg_kernel<<<(n_edges + 255) / 256, 256, 0, stream>>>(sources, targets, deg2, n_nodes, n_edges);

    // 2. exclusive scan deg2 -> off2
    int nblk = (n2 + 2047) / 2048;
    scan_pass1<<<nblk, 256, 0, stream>>>(deg2, bsums, n2);
    scan_pass2<<<1, 1024, 0, stream>>>(bsums, nblk);
    scan_pass3<<<nblk, 256, 0, stream>>>(deg2, bsums, off2, n2);

    // 3. cursors = offsets copy, then scatter neighbor ids
    hipMemcpyAsync(cur2, off2, (size_t)n2 * 4, hipMemcpyDeviceToDevice, stream);
    scatter_kernel<<<(n_edges + 255) / 256, 256, 0, stream>>>(sources, targets, cur2, nbr,
                                                              n_nodes, n_edges);

    // 4. init features + norms; counts via binary search
    int node_thr = n_nodes * CHANNELS;
    init_kernel<<<(node_thr + 255) / 256, 256, 0, stream>>>(nodes, emb, deg2, x0, norm, norm_t, n_nodes);
    counts_kernel<<<(n_graphs + 255) / 256, 256, 0, stream>>>(batch, counts, n_nodes, n_graphs);

    // 5. layers (ping-pong)
    float* xin = x0; float* xout = x1;
    for (int l = 0; l < LAYERS; l++) {
        const float* wbase = conv_w + (size_t)l * 2 * CHANNELS * CHANNELS;
        layer_kernel<<<(node_thr + 255) / 256, 256, 0, stream>>>(off2, nbr, wbase, norm, norm_t,
                                                                 xin, xout, n_nodes, n_edges);
        float* tmp = xin; xin = xout; xout = tmp;
    }
    // after 8 layers, result is back in x0 (== xin)

    // 6. pool + head
    int pool_blocks = (n_nodes + POOL_CHUNK - 1) / POOL_CHUNK;
    pool_kernel<<<pool_blocks, 256, 0, stream>>>(batch, xin, g, n_nodes);
    mlp_kernel<<<n_graphs, 256, 0, stream>>>(g, counts, hidden_w, hidden_b, out_w, out);
}

// Round 3
// 3029.270 us; speedup vs baseline: 2.0669x; 1.0782x over previous
//
#include <hip/hip_runtime.h>

#define CHANNELS 32
#define HIDDEN 1024
#define LAYERS 8

// ---------------- degree count (int atomics, once) ----------------

__global__ void deg_kernel(const int* __restrict__ src, const int* __restrict__ tgt,
                           int* __restrict__ deg2, int n_nodes, int n_edges) {
    int e = blockIdx.x * blockDim.x + threadIdx.x;
    if (e < n_edges) {
        atomicAdd(&deg2[tgt[e]], 1);            // in-degree
        atomicAdd(&deg2[n_nodes + src[e]], 1);  // out-degree
    }
}

// ---------------- 3-kernel exclusive prefix scan over deg2[0..n2) ----------------

__global__ __launch_bounds__(256)
void scan_pass1(const int* __restrict__ deg, int* __restrict__ bs, int n) {
    __shared__ int sh[256];
    int t = threadIdx.x;
    int base = blockIdx.x * 2048 + t * 8;
    int s = 0;
#pragma unroll
    for (int j = 0; j < 8; j++) { int idx = base + j; if (idx < n) s += deg[idx]; }
    sh[t] = s; __syncthreads();
    for (int st = 128; st > 0; st >>= 1) { if (t < st) sh[t] += sh[t + st]; __syncthreads(); }
    if (t == 0) bs[blockIdx.x] = sh[0];
}

__global__ void scan_pass2(int* __restrict__ bs, int nb) {
    __shared__ int sh[1024];
    int t = threadIdx.x;
    int v = (t < nb) ? bs[t] : 0;
    sh[t] = v; __syncthreads();
    for (int off = 1; off < 1024; off <<= 1) {
        int u = (t >= off) ? sh[t - off] : 0; __syncthreads();
        sh[t] += u; __syncthreads();
    }
    if (t < nb) bs[t] = sh[t] - v;   // exclusive
}

__global__ __launch_bounds__(256)
void scan_pass3(const int* __restrict__ deg, const int* __restrict__ bs,
                int* __restrict__ off, int n) {
    __shared__ int sh[256];
    int t = threadIdx.x;
    int base = blockIdx.x * 2048 + t * 8;
    int v[8]; int s = 0;
#pragma unroll
    for (int j = 0; j < 8; j++) { int idx = base + j; v[j] = (idx < n) ? deg[idx] : 0; s += v[j]; }
    sh[t] = s; __syncthreads();
    for (int st = 1; st < 256; st <<= 1) {
        int u = (t >= st) ? sh[t - st] : 0; __syncthreads();
        sh[t] += u; __syncthreads();
    }
    int acc = bs[blockIdx.x] + sh[t] - s;   // exclusive base for this thread
#pragma unroll
    for (int j = 0; j < 8; j++) { int idx = base + j; if (idx < n) off[idx] = acc; acc += v[j]; }
}

// ---------------- scatter edges into neighbor lists (int atomics, once) ----------------

__global__ __launch_bounds__(256)
void scatter_kernel(const int* __restrict__ src, const int* __restrict__ tgt,
                    int* __restrict__ cur2, int* __restrict__ nbr,
                    int n_nodes, int n_edges) {
    int e = blockIdx.x * blockDim.x + threadIdx.x;
    if (e >= n_edges) return;
    int s = src[e], t = tgt[e];
    int p = atomicAdd(&cur2[t], 1);            nbr[p] = s;   // in-neighbors of t
    int q = atomicAdd(&cur2[n_nodes + s], 1);  nbr[q] = t;   // out-neighbors of s
}

// ---------------- init: x = emb[nodes], norms from degrees ----------------

__global__ __launch_bounds__(256)
void init_kernel(const int* __restrict__ nodes, const float* __restrict__ emb,
                 const int* __restrict__ deg2,
                 float* __restrict__ x, float* __restrict__ norm,
                 float* __restrict__ norm_t, int n_nodes) {
    int gid = blockIdx.x * blockDim.x + threadIdx.x;
    int i = gid >> 5, c = gid & 31;
    if (i >= n_nodes) return;
    x[gid] = emb[nodes[i] * CHANNELS + c];
    if (c == 0) {
        norm[i]   = 1.0f / (1.0f + (float)deg2[i]);
        norm_t[i] = 1.0f / (1.0f + (float)deg2[n_nodes + i]);
    }
}

// ---------------- counts via binary search over sorted batch ----------------

__global__ void counts_kernel(const int* __restrict__ batch, float* __restrict__ counts,
                              int n_nodes, int n_graphs) {
    int b = blockIdx.x * blockDim.x + threadIdx.x;
    if (b >= n_graphs) return;
    int lo = 0, hi = n_nodes;
    while (lo < hi) { int mid = (lo + hi) >> 1; if (batch[mid] < b) lo = mid + 1; else hi = mid; }
    int s = lo;
    lo = 0; hi = n_nodes;
    while (lo < hi) { int mid = (lo + hi) >> 1; if (batch[mid] < b + 1) lo = mid + 1; else hi = mid; }
    counts[b] = (float)(lo - s);
}

// ---------------- fused layer: gather both directions + matvecs + residual ----------------
// Gather loops issue 4 independent loads per iteration (MLP fix): out-of-range
// neighbor slots are clamped to the node's own row (L1-hot) and their adds are
// predicated off. With m <= 32 and unroll stride 4, max shfl lane index is 31.

__global__ __launch_bounds__(256)
void layer_kernel(const int* __restrict__ off2, const int* __restrict__ nbr,
                  const float* __restrict__ wbase,
                  const float* __restrict__ norm, const float* __restrict__ norm_t,
                  const float* __restrict__ xin, float* __restrict__ xout,
                  int n_nodes, int n_edges) {
    __shared__ float w0[CHANNELS][CHANNELS];
    __shared__ float w1[CHANNELS][CHANNELS];
    int tid = threadIdx.x;
    for (int idx = tid; idx < CHANNELS * CHANNELS; idx += 256) {
        w0[idx >> 5][idx & 31] = wbase[idx];
        w1[idx >> 5][idx & 31] = wbase[CHANNELS * CHANNELS + idx];
    }
    __syncthreads();
    int gid = blockIdx.x * 256 + tid;
    int i = gid >> 5, c = gid & 31;
    if (i >= n_nodes) return;

    float xv = xin[gid];

    int b_in  = off2[i];
    int e_in  = (i + 1 < n_nodes) ? off2[i + 1] : n_edges;
    int b_out = off2[n_nodes + i];
    int e_out = (i + 1 < n_nodes) ? off2[n_nodes + i + 1] : 2 * n_edges;

    float a1 = 0.f;
    {
        int deg = e_in - b_in;
        int nbl = (c < deg) ? nbr[b_in + c] : 0;
        int m = deg < 32 ? deg : 32;
        for (int j = 0; j < m; j += 4) {
            int n0 = __shfl(nbl, j, 32);
            int n1 = __shfl(nbl, j + 1, 32);
            int n2 = __shfl(nbl, j + 2, 32);
            int n3 = __shfl(nbl, j + 3, 32);
            n1 = (j + 1 < m) ? n1 : i;
            n2 = (j + 2 < m) ? n2 : i;
            n3 = (j + 3 < m) ? n3 : i;
            float v0 = xin[n0 * CHANNELS + c];
            float v1 = xin[n1 * CHANNELS + c];
            float v2 = xin[n2 * CHANNELS + c];
            float v3 = xin[n3 * CHANNELS + c];
            a1 += v0;
            a1 += (j + 1 < m) ? v1 : 0.f;
            a1 += (j + 2 < m) ? v2 : 0.f;
            a1 += (j + 3 < m) ? v3 : 0.f;
        }
        for (int e = b_in + 32; e < e_in; e++) a1 += xin[nbr[e] * CHANNELS + c];
    }
    float a2 = 0.f;
    {
        int deg = e_out - b_out;
        int nbl = (c < deg) ? nbr[b_out + c] : 0;
        int m = deg < 32 ? deg : 32;
        for (int j = 0; j < m; j += 4) {
            int n0 = __shfl(nbl, j, 32);
            int n1 = __shfl(nbl, j + 1, 32);
            int n2 = __shfl(nbl, j + 2, 32);
            int n3 = __shfl(nbl, j + 3, 32);
            n1 = (j + 1 < m) ? n1 : i;
            n2 = (j + 2 < m) ? n2 : i;
            n3 = (j + 3 < m) ? n3 : i;
            float v0 = xin[n0 * CHANNELS + c];
            float v1 = xin[n1 * CHANNELS + c];
            float v2 = xin[n2 * CHANNELS + c];
            float v3 = xin[n3 * CHANNELS + c];
            a2 += v0;
            a2 += (j + 1 < m) ? v1 : 0.f;
            a2 += (j + 2 < m) ? v2 : 0.f;
            a2 += (j + 3 < m) ? v3 : 0.f;
        }
        for (int e = b_out + 32; e < e_out; e++) a2 += xin[nbr[e] * CHANNELS + c];
    }

    a1 = norm[i]   * (xv + a1);
    a2 = norm_t[i] * (xv + a2);

    float y1 = 0.f, y2 = 0.f;
#pragma unroll
    for (int k = 0; k < CHANNELS; k++) {
        float a1k = __shfl(a1, k, 32);
        float a2k = __shfl(a2, k, 32);
        y1 += a1k * w0[k][c];
        y2 += a2k * w1[k][c];
    }
    xout[gid] = xv + fmaxf(y1, 0.f) + fmaxf(y2, 0.f);
}

// ---------------- pooling: run-length accumulate over sorted batch ----------------

#define POOL_CHUNK 2048

__global__ __launch_bounds__(256)
void pool_kernel(const int* __restrict__ batch, const float* __restrict__ x,
                 float* __restrict__ g, int n_nodes) {
    int c = threadIdx.x & 31;
    int r = threadIdx.x >> 5;          // 0..7
    int base = blockIdx.x * POOL_CHUNK;
    float acc = 0.f;
    int cur = -1;
    for (int it = 0; it < POOL_CHUNK / 8; it++) {
        int node = base + it * 8 + r;
        if (node >= n_nodes) break;
        int b = batch[node];
        if (b != cur) {
            if (cur >= 0) atomicAdd(&g[cur * CHANNELS + c], acc);
            acc = 0.f;
            cur = b;
        }
        acc += x[node * CHANNELS + c];
    }
    if (cur >= 0) atomicAdd(&g[cur * CHANNELS + c], acc);
}

// ---------------- MLP head: one block per graph ----------------

__global__ __launch_bounds__(256)
void mlp_kernel(const float* __restrict__ g, const float* __restrict__ counts,
                const float* __restrict__ hidden_w, const float* __restrict__ hidden_b,
                const float* __restrict__ out_w, float* __restrict__ out) {
    __shared__ float grow[CHANNELS];
    __shared__ float red[256];
    int graph = blockIdx.x;
    int tid = threadIdx.x;
    if (tid < CHANNELS) grow[tid] = g[graph * CHANNELS + tid] / counts[graph];
    __syncthreads();
    float partial = 0.f;
    for (int q = 0; q < HIDDEN / 256; q++) {
        int j = q * 256 + tid;
        float h = hidden_b[j];
#pragma unroll
        for (int k = 0; k < CHANNELS; k++) h += grow[k] * hidden_w[k * HIDDEN + j];
        partial += fmaxf(h, 0.f) * out_w[j];
    }
    red[tid] = partial;
    __syncthreads();
    for (int s = 128; s > 0; s >>= 1) {
        if (tid < s) red[tid] += red[tid + s];
        __syncthreads();
    }
    if (tid == 0) out[graph] = red[0];
}

// ---------------- launch ----------------

extern "C" void kernel_launch(void* const* d_in, const int* in_sizes, int n_in,
                              void* d_out, int out_size, void* d_ws, size_t ws_size,
                              hipStream_t stream) {
    const int*   nodes    = (const int*)d_in[0];
    const int*   sources  = (const int*)d_in[1];
    const int*   targets  = (const int*)d_in[2];
    const int*   batch    = (const int*)d_in[3];
    const float* emb      = (const float*)d_in[4];
    const float* conv_w   = (const float*)d_in[5];
    const float* hidden_w = (const float*)d_in[6];
    const float* hidden_b = (const float*)d_in[7];
    const float* out_w    = (const float*)d_in[8];
    float* out = (float*)d_out;

    const int n_nodes  = in_sizes[0];
    const int n_edges  = in_sizes[1];
    const int n_graphs = out_size;
    const int n2 = 2 * n_nodes;

    char* ws = (char*)d_ws;
    float* x0     = (float*)ws; ws += (size_t)n_nodes * CHANNELS * 4;
    float* x1     = (float*)ws; ws += (size_t)n_nodes * CHANNELS * 4;
    float* norm   = (float*)ws; ws += (size_t)n_nodes * 4;
    float* norm_t = (float*)ws; ws += (size_t)n_nodes * 4;
    int*   deg2   = (int*)ws;   ws += (size_t)n2 * 4;
    int*   off2   = (int*)ws;   ws += (size_t)n2 * 4;
    int*   cur2   = (int*)ws;   ws += (size_t)n2 * 4;
    int*   nbr    = (int*)ws;   ws += (size_t)2 * n_edges * 4;
    int*   bsums  = (int*)ws;   ws += 4096;
    float* g      = (float*)ws; ws += (size_t)n_graphs * CHANNELS * 4;
    float* counts = (float*)ws; ws += (size_t)n_graphs * 4;

    hipMemsetAsync(deg2, 0, (size_t)n2 * 4, stream);
    hipMemsetAsync(g, 0, (size_t)n_graphs * CHANNELS * 4, stream);

    // 1. degrees
    deg_kernel<<<(n_edges + 255) / 256, 256, 0, stream>>>(sources, targets, deg2, n_nodes, n_edges);

    // 2. exclusive scan deg2 -> off2
    int nblk = (n2 + 2047) / 2048;
    scan_pass1<<<nblk, 256, 0, stream>>>(deg2, bsums, n2);
    scan_pass2<<<1, 1024, 0, stream>>>(bsums, nblk);
    scan_pass3<<<nblk, 256, 0, stream>>>(deg2, bsums, off2, n2);

    // 3. cursors = offsets copy, then scatter neighbor ids
    hipMemcpyAsync(cur2, off2, (size_t)n2 * 4, hipMemcpyDeviceToDevice, stream);
    scatter_kernel<<<(n_edges + 255) / 256, 256, 0, stream>>>(sources, targets, cur2, nbr,
                                                              n_nodes, n_edges);

    // 4. init features + norms; counts via binary search
    int node_thr = n_nodes * CHANNELS;
    init_kernel<<<(node_thr + 255) / 256, 256, 0, stream>>>(nodes, emb, deg2, x0, norm, norm_t, n_nodes);
    counts_kernel<<<(n_graphs + 255) / 256, 256, 0, stream>>>(batch, counts, n_nodes, n_graphs);

    // 5. layers (ping-pong)
    float* xin = x0; float* xout = x1;
    for (int l = 0; l < LAYERS; l++) {
        const float* wbase = conv_w + (size_t)l * 2 * CHANNELS * CHANNELS;
        layer_kernel<<<(node_thr + 255) / 256, 256, 0, stream>>>(off2, nbr, wbase, norm, norm_t,
                                                                 xin, xout, n_nodes, n_edges);
        float* tmp = xin; xin = xout; xout = tmp;
    }
    // after 8 layers, result is back in x0 (== xin)

    // 6. pool + head
    int pool_blocks = (n_nodes + POOL_CHUNK - 1) / POOL_CHUNK;
    pool_kernel<<<pool_blocks, 256, 0, stream>>>(batch, xin, g, n_nodes);
    mlp_kernel<<<n_graphs, 256, 0, stream>>>(g, counts, hidden_w, hidden_b, out_w, out);
}

// Round 4
// 2320.697 us; speedup vs baseline: 2.6980x; 1.3053x over previous
//
#include <hip/hip_runtime.h>

#define CHANNELS 32
#define HIDDEN 1024
#define LAYERS 8
#define NRANGE 8

typedef __attribute__((ext_vector_type(8))) short short8;
typedef __attribute__((ext_vector_type(4))) float float4v;

__device__ __forceinline__ short f2bf_rne(float f) {
    union { float f; unsigned u; } v; v.f = f;
    unsigned r = v.u + 0x7fffu + ((v.u >> 16) & 1u);
    return (short)(r >> 16);
}
__device__ __forceinline__ float bf2f(short h) {
    union { float f; unsigned u; } v; v.u = ((unsigned)(unsigned short)h) << 16;
    return v.f;
}

// ---------------- degree count, range-split (XCD-affine) ----------------

__global__ __launch_bounds__(256)
void deg_range_kernel(const int* __restrict__ src, const int* __restrict__ tgt,
                      int* __restrict__ deg2, int n_nodes, int n_edges, int rsh) {
    int r = blockIdx.x & (NRANGE - 1);
    int chunk = blockIdx.x >> 3;
    int base = chunk * 2048;
#pragma unroll
    for (int j = 0; j < 8; j++) {
        int e = base + j * 256 + threadIdx.x;
        if (e < n_edges) {
            int t = tgt[e];
            int s = src[e];
            if ((t >> rsh) == r) atomicAdd(&deg2[t], 1);
            if ((s >> rsh) == r) atomicAdd(&deg2[n_nodes + s], 1);
        }
    }
}

// ---------------- 3-kernel exclusive prefix scan over deg2[0..n2) ----------------

__global__ __launch_bounds__(256)
void scan_pass1(const int* __restrict__ deg, int* __restrict__ bs, int n) {
    __shared__ int sh[256];
    int t = threadIdx.x;
    int base = blockIdx.x * 2048 + t * 8;
    int s = 0;
#pragma unroll
    for (int j = 0; j < 8; j++) { int idx = base + j; if (idx < n) s += deg[idx]; }
    sh[t] = s; __syncthreads();
    for (int st = 128; st > 0; st >>= 1) { if (t < st) sh[t] += sh[t + st]; __syncthreads(); }
    if (t == 0) bs[blockIdx.x] = sh[0];
}

__global__ void scan_pass2(int* __restrict__ bs, int nb) {
    __shared__ int sh[1024];
    int t = threadIdx.x;
    int v = (t < nb) ? bs[t] : 0;
    sh[t] = v; __syncthreads();
    for (int off = 1; off < 1024; off <<= 1) {
        int u = (t >= off) ? sh[t - off] : 0; __syncthreads();
        sh[t] += u; __syncthreads();
    }
    if (t < nb) bs[t] = sh[t] - v;   // exclusive
}

__global__ __launch_bounds__(256)
void scan_pass3(const int* __restrict__ deg, const int* __restrict__ bs,
                int* __restrict__ off, int n) {
    __shared__ int sh[256];
    int t = threadIdx.x;
    int base = blockIdx.x * 2048 + t * 8;
    int v[8]; int s = 0;
#pragma unroll
    for (int j = 0; j < 8; j++) { int idx = base + j; v[j] = (idx < n) ? deg[idx] : 0; s += v[j]; }
    sh[t] = s; __syncthreads();
    for (int st = 1; st < 256; st <<= 1) {
        int u = (t >= st) ? sh[t - st] : 0; __syncthreads();
        sh[t] += u; __syncthreads();
    }
    int acc = bs[blockIdx.x] + sh[t] - s;
#pragma unroll
    for (int j = 0; j < 8; j++) { int idx = base + j; if (idx < n) off[idx] = acc; acc += v[j]; }
}

// ---------------- scatter edges into neighbor lists, range-split ----------------

__global__ __launch_bounds__(256)
void scatter_range_kernel(const int* __restrict__ src, const int* __restrict__ tgt,
                          int* __restrict__ cur2, int* __restrict__ nbr,
                          int n_nodes, int n_edges, int rsh) {
    int r = blockIdx.x & (NRANGE - 1);
    int chunk = blockIdx.x >> 3;
    int base = chunk * 2048;
#pragma unroll
    for (int j = 0; j < 8; j++) {
        int e = base + j * 256 + threadIdx.x;
        if (e < n_edges) {
            int s = src[e], t = tgt[e];
            if ((t >> rsh) == r) { int p = atomicAdd(&cur2[t], 1);           nbr[p] = s; }
            if ((s >> rsh) == r) { int q = atomicAdd(&cur2[n_nodes + s], 1); nbr[q] = t; }
        }
    }
}

// ---------------- init: x = emb[nodes], norms from degrees ----------------

__global__ __launch_bounds__(256)
void init_kernel(const int* __restrict__ nodes, const float* __restrict__ emb,
                 const int* __restrict__ deg2,
                 float* __restrict__ x, float* __restrict__ norm,
                 float* __restrict__ norm_t, int n_nodes) {
    int gid = blockIdx.x * blockDim.x + threadIdx.x;
    int i = gid >> 5, c = gid & 31;
    if (i >= n_nodes) return;
    x[gid] = emb[nodes[i] * CHANNELS + c];
    if (c == 0) {
        norm[i]   = 1.0f / (1.0f + (float)deg2[i]);
        norm_t[i] = 1.0f / (1.0f + (float)deg2[n_nodes + i]);
    }
}

// ---------------- counts via binary search over sorted batch ----------------

__global__ void counts_kernel(const int* __restrict__ batch, float* __restrict__ counts,
                              int n_nodes, int n_graphs) {
    int b = blockIdx.x * blockDim.x + threadIdx.x;
    if (b >= n_graphs) return;
    int lo = 0, hi = n_nodes;
    while (lo < hi) { int mid = (lo + hi) >> 1; if (batch[mid] < b) lo = mid + 1; else hi = mid; }
    int s = lo;
    lo = 0; hi = n_nodes;
    while (lo < hi) { int mid = (lo + hi) >> 1; if (batch[mid] < b + 1) lo = mid + 1; else hi = mid; }
    counts[b] = (float)(lo - s);
}

// ---------------- fused layer: gather into LDS, then split-bf16 MFMA matvecs ----
// Block = 64 nodes, 256 threads (4 waves). Phase 1: (node,c) threads gather both
// directions, normalize, split a = a_hi + a_lo (bf16 pair), stash in LDS. Phase 2:
// wave w computes nodes [16w,16w+16): D = A@W via mfma_f32_16x16x32_bf16 with
// 3-term split product (hi*hi + lo*hi + hi*lo) ~= fp32 accuracy. C/D layout:
// col=lane&15 (out channel), row=quad*4+reg (node). A: A[m=lane&15][k=quad*8+j].
// B: B[k=quad*8+j][n=lane&15], staged transposed in LDS as W[n][k].

__global__ __launch_bounds__(256)
void layer_mfma(const int* __restrict__ off2, const int* __restrict__ nbr,
                const float* __restrict__ wbase,
                const float* __restrict__ norm, const float* __restrict__ norm_t,
                const float* __restrict__ xin, float* __restrict__ xout,
                int n_nodes, int n_edges) {
    __shared__ short A1h[64][32], A1l[64][32], A2h[64][32], A2l[64][32];
    __shared__ short W0h[32][32], W0l[32][32], W1h[32][32], W1l[32][32]; // [n][k]
    __shared__ float X[64][33];

    int tid = threadIdx.x;
    // stage weights: transpose + hi/lo split
    for (int idx = tid; idx < CHANNELS * CHANNELS; idx += 256) {
        int k = idx >> 5, n = idx & 31;
        float w0 = wbase[idx];
        float w1 = wbase[CHANNELS * CHANNELS + idx];
        short h0 = f2bf_rne(w0); W0h[n][k] = h0; W0l[n][k] = f2bf_rne(w0 - bf2f(h0));
        short h1 = f2bf_rne(w1); W1h[n][k] = h1; W1l[n][k] = f2bf_rne(w1 - bf2f(h1));
    }

    int c = tid & 31, sub = tid >> 5;
    int nodeblock = blockIdx.x * 64;

    for (int pass = 0; pass < 8; pass++) {
        int local = pass * 8 + sub;
        int i = nodeblock + local;
        if (i < n_nodes) {
            float xv = xin[i * CHANNELS + c];

            int b_in  = off2[i];
            int e_in  = (i + 1 < n_nodes) ? off2[i + 1] : n_edges;
            int b_out = off2[n_nodes + i];
            int e_out = (i + 1 < n_nodes) ? off2[n_nodes + i + 1] : 2 * n_edges;

            float a1 = 0.f;
            {
                int deg = e_in - b_in;
                int nbl = (c < deg) ? nbr[b_in + c] : 0;
                int m = deg < 32 ? deg : 32;
                for (int j = 0; j < m; j += 4) {
                    int n0 = __shfl(nbl, j, 32);
                    int n1 = __shfl(nbl, j + 1, 32);
                    int n2 = __shfl(nbl, j + 2, 32);
                    int n3 = __shfl(nbl, j + 3, 32);
                    n1 = (j + 1 < m) ? n1 : i;
                    n2 = (j + 2 < m) ? n2 : i;
                    n3 = (j + 3 < m) ? n3 : i;
                    float v0 = xin[n0 * CHANNELS + c];
                    float v1 = xin[n1 * CHANNELS + c];
                    float v2 = xin[n2 * CHANNELS + c];
                    float v3 = xin[n3 * CHANNELS + c];
                    a1 += v0;
                    a1 += (j + 1 < m) ? v1 : 0.f;
                    a1 += (j + 2 < m) ? v2 : 0.f;
                    a1 += (j + 3 < m) ? v3 : 0.f;
                }
                for (int e = b_in + 32; e < e_in; e++) a1 += xin[nbr[e] * CHANNELS + c];
            }
            float a2 = 0.f;
            {
                int deg = e_out - b_out;
                int nbl = (c < deg) ? nbr[b_out + c] : 0;
                int m = deg < 32 ? deg : 32;
                for (int j = 0; j < m; j += 4) {
                    int n0 = __shfl(nbl, j, 32);
                    int n1 = __shfl(nbl, j + 1, 32);
                    int n2 = __shfl(nbl, j + 2, 32);
                    int n3 = __shfl(nbl, j + 3, 32);
                    n1 = (j + 1 < m) ? n1 : i;
                    n2 = (j + 2 < m) ? n2 : i;
                    n3 = (j + 3 < m) ? n3 : i;
                    float v0 = xin[n0 * CHANNELS + c];
                    float v1 = xin[n1 * CHANNELS + c];
                    float v2 = xin[n2 * CHANNELS + c];
                    float v3 = xin[n3 * CHANNELS + c];
                    a2 += v0;
                    a2 += (j + 1 < m) ? v1 : 0.f;
                    a2 += (j + 2 < m) ? v2 : 0.f;
                    a2 += (j + 3 < m) ? v3 : 0.f;
                }
                for (int e = b_out + 32; e < e_out; e++) a2 += xin[nbr[e] * CHANNELS + c];
            }

            a1 = norm[i]   * (xv + a1);
            a2 = norm_t[i] * (xv + a2);
            X[local][c] = xv;
            short h1s = f2bf_rne(a1);
            A1h[local][c] = h1s; A1l[local][c] = f2bf_rne(a1 - bf2f(h1s));
            short h2s = f2bf_rne(a2);
            A2h[local][c] = h2s; A2l[local][c] = f2bf_rne(a2 - bf2f(h2s));
        }
    }
    __syncthreads();

    int wv = tid >> 6, lane = tid & 63;
    int m = lane & 15, quad = lane >> 4;
    int row0 = wv * 16;

    short8 a1h = *(const short8*)&A1h[row0 + m][quad * 8];
    short8 a1l = *(const short8*)&A1l[row0 + m][quad * 8];
    short8 a2h = *(const short8*)&A2h[row0 + m][quad * 8];
    short8 a2l = *(const short8*)&A2l[row0 + m][quad * 8];

    float4v dd[4];
#pragma unroll
    for (int h = 0; h < 2; h++) {
        int n0 = h * 16 + m;
        short8 b0h = *(const short8*)&W0h[n0][quad * 8];
        short8 b0l = *(const short8*)&W0l[n0][quad * 8];
        short8 b1h = *(const short8*)&W1h[n0][quad * 8];
        short8 b1l = *(const short8*)&W1l[n0][quad * 8];
        float4v d1 = {0.f, 0.f, 0.f, 0.f};
        d1 = __builtin_amdgcn_mfma_f32_16x16x32_bf16(a1h, b0h, d1, 0, 0, 0);
        d1 = __builtin_amdgcn_mfma_f32_16x16x32_bf16(a1l, b0h, d1, 0, 0, 0);
        d1 = __builtin_amdgcn_mfma_f32_16x16x32_bf16(a1h, b0l, d1, 0, 0, 0);
        float4v d2 = {0.f, 0.f, 0.f, 0.f};
        d2 = __builtin_amdgcn_mfma_f32_16x16x32_bf16(a2h, b1h, d2, 0, 0, 0);
        d2 = __builtin_amdgcn_mfma_f32_16x16x32_bf16(a2l, b1h, d2, 0, 0, 0);
        d2 = __builtin_amdgcn_mfma_f32_16x16x32_bf16(a2h, b1l, d2, 0, 0, 0);
        dd[h * 2] = d1; dd[h * 2 + 1] = d2;
    }

#pragma unroll
    for (int h = 0; h < 2; h++) {
        float4v d1 = dd[h * 2], d2 = dd[h * 2 + 1];
#pragma unroll
        for (int r = 0; r < 4; r++) {
            int local = row0 + quad * 4 + r;
            int node = nodeblock + local;
            if (node < n_nodes) {
                float v = X[local][h * 16 + m] + fmaxf(d1[r], 0.f) + fmaxf(d2[r], 0.f);
                xout[node * CHANNELS + h * 16 + m] = v;
            }
        }
    }
}

// ---------------- pooling: run-length accumulate over sorted batch ----------------

#define POOL_CHUNK 2048

__global__ __launch_bounds__(256)
void pool_kernel(const int* __restrict__ batch, const float* __restrict__ x,
                 float* __restrict__ g, int n_nodes) {
    int c = threadIdx.x & 31;
    int r = threadIdx.x >> 5;
    int base = blockIdx.x * POOL_CHUNK;
    float acc = 0.f;
    int cur = -1;
    for (int it = 0; it < POOL_CHUNK / 8; it++) {
        int node = base + it * 8 + r;
        if (node >= n_nodes) break;
        int b = batch[node];
        if (b != cur) {
            if (cur >= 0) atomicAdd(&g[cur * CHANNELS + c], acc);
            acc = 0.f;
            cur = b;
        }
        acc += x[node * CHANNELS + c];
    }
    if (cur >= 0) atomicAdd(&g[cur * CHANNELS + c], acc);
}

// ---------------- MLP head: one block per graph ----------------

__global__ __launch_bounds__(256)
void mlp_kernel(const float* __restrict__ g, const float* __restrict__ counts,
                const float* __restrict__ hidden_w, const float* __restrict__ hidden_b,
                const float* __restrict__ out_w, float* __restrict__ out) {
    __shared__ float grow[CHANNELS];
    __shared__ float red[256];
    int graph = blockIdx.x;
    int tid = threadIdx.x;
    if (tid < CHANNELS) grow[tid] = g[graph * CHANNELS + tid] / counts[graph];
    __syncthreads();
    float partial = 0.f;
    for (int q = 0; q < HIDDEN / 256; q++) {
        int j = q * 256 + tid;
        float h = hidden_b[j];
#pragma unroll
        for (int k = 0; k < CHANNELS; k++) h += grow[k] * hidden_w[k * HIDDEN + j];
        partial += fmaxf(h, 0.f) * out_w[j];
    }
    red[tid] = partial;
    __syncthreads();
    for (int s = 128; s > 0; s >>= 1) {
        if (tid < s) red[tid] += red[tid + s];
        __syncthreads();
    }
    if (tid == 0) out[graph] = red[0];
}

// ---------------- launch ----------------

extern "C" void kernel_launch(void* const* d_in, const int* in_sizes, int n_in,
                              void* d_out, int out_size, void* d_ws, size_t ws_size,
                              hipStream_t stream) {
    const int*   nodes    = (const int*)d_in[0];
    const int*   sources  = (const int*)d_in[1];
    const int*   targets  = (const int*)d_in[2];
    const int*   batch    = (const int*)d_in[3];
    const float* emb      = (const float*)d_in[4];
    const float* conv_w   = (const float*)d_in[5];
    const float* hidden_w = (const float*)d_in[6];
    const float* hidden_b = (const float*)d_in[7];
    const float* out_w    = (const float*)d_in[8];
    float* out = (float*)d_out;

    const int n_nodes  = in_sizes[0];
    const int n_edges  = in_sizes[1];
    const int n_graphs = out_size;
    const int n2 = 2 * n_nodes;

    int rsh = 0;
    while (((n_nodes - 1) >> rsh) >= NRANGE) rsh++;

    char* ws = (char*)d_ws;
    float* x0     = (float*)ws; ws += (size_t)n_nodes * CHANNELS * 4;
    float* x1     = (float*)ws; ws += (size_t)n_nodes * CHANNELS * 4;
    float* norm   = (float*)ws; ws += (size_t)n_nodes * 4;
    float* norm_t = (float*)ws; ws += (size_t)n_nodes * 4;
    int*   deg2   = (int*)ws;   ws += (size_t)n2 * 4;
    int*   off2   = (int*)ws;   ws += (size_t)n2 * 4;
    int*   cur2   = (int*)ws;   ws += (size_t)n2 * 4;
    int*   nbr    = (int*)ws;   ws += (size_t)2 * n_edges * 4;
    int*   bsums  = (int*)ws;   ws += 4096;
    float* g      = (float*)ws; ws += (size_t)n_graphs * CHANNELS * 4;
    float* counts = (float*)ws; ws += (size_t)n_graphs * 4;

    hipMemsetAsync(deg2, 0, (size_t)n2 * 4, stream);
    hipMemsetAsync(g, 0, (size_t)n_graphs * CHANNELS * 4, stream);

    int echunks = (n_edges + 2047) / 2048;

    // 1. degrees (range-split, XCD-affine)
    deg_range_kernel<<<echunks * NRANGE, 256, 0, stream>>>(sources, targets, deg2,
                                                           n_nodes, n_edges, rsh);

    // 2. exclusive scan deg2 -> off2
    int nblk = (n2 + 2047) / 2048;
    scan_pass1<<<nblk, 256, 0, stream>>>(deg2, bsums, n2);
    scan_pass2<<<1, 1024, 0, stream>>>(bsums, nblk);
    scan_pass3<<<nblk, 256, 0, stream>>>(deg2, bsums, off2, n2);

    // 3. cursors = offsets copy, then scatter neighbor ids (range-split)
    hipMemcpyAsync(cur2, off2, (size_t)n2 * 4, hipMemcpyDeviceToDevice, stream);
    scatter_range_kernel<<<echunks * NRANGE, 256, 0, stream>>>(sources, targets, cur2, nbr,
                                                               n_nodes, n_edges, rsh);

    // 4. init features + norms; counts via binary search
    int node_thr = n_nodes * CHANNELS;
    init_kernel<<<(node_thr + 255) / 256, 256, 0, stream>>>(nodes, emb, deg2, x0, norm, norm_t, n_nodes);
    counts_kernel<<<(n_graphs + 255) / 256, 256, 0, stream>>>(batch, counts, n_nodes, n_graphs);

    // 5. layers (ping-pong), 64 nodes per block
    float* xin = x0; float* xout = x1;
    int lblocks = (n_nodes + 63) / 64;
    for (int l = 0; l < LAYERS; l++) {
        const float* wbase = conv_w + (size_t)l * 2 * CHANNELS * CHANNELS;
        layer_mfma<<<lblocks, 256, 0, stream>>>(off2, nbr, wbase, norm, norm_t,
                                                xin, xout, n_nodes, n_edges);
        float* tmp = xin; xin = xout; xout = tmp;
    }
    // after 8 layers, result is in x0 (== xin)

    // 6. pool + head
    int pool_blocks = (n_nodes + POOL_CHUNK - 1) / POOL_CHUNK;
    pool_kernel<<<pool_blocks, 256, 0, stream>>>(batch, xin, g, n_nodes);
    mlp_kernel<<<n_graphs, 256, 0, stream>>>(g, counts, hidden_w, hidden_b, out_w, out);
}

// Round 5
// 2026.456 us; speedup vs baseline: 3.0898x; 1.1452x over previous
//
#include <hip/hip_runtime.h>

#define CHANNELS 32
#define HIDDEN 1024
#define LAYERS 8
#define NRANGE 8

typedef __attribute__((ext_vector_type(8))) short short8;
typedef __attribute__((ext_vector_type(4))) float float4v;

__device__ __forceinline__ short f2bf_rne(float f) {
    union { float f; unsigned u; } v; v.f = f;
    unsigned r = v.u + 0x7fffu + ((v.u >> 16) & 1u);
    return (short)(r >> 16);
}
__device__ __forceinline__ float bf2f(short h) {
    union { float f; unsigned u; } v; v.u = ((unsigned)(unsigned short)h) << 16;
    return v.f;
}
__device__ __forceinline__ float bfu2f(unsigned short h) {
    union { float f; unsigned u; } v; v.u = ((unsigned)h) << 16;
    return v.f;
}

// ---------------- degree count, range-split (XCD-affine), nt edge reads -------

__global__ __launch_bounds__(256)
void deg_range_kernel(const int* __restrict__ src, const int* __restrict__ tgt,
                      int* __restrict__ deg2, int n_nodes, int n_edges, int rsh) {
    int r = blockIdx.x & (NRANGE - 1);
    int chunk = blockIdx.x >> 3;
    int base = chunk * 2048;
#pragma unroll
    for (int j = 0; j < 8; j++) {
        int e = base + j * 256 + threadIdx.x;
        if (e < n_edges) {
            int t = __builtin_nontemporal_load(tgt + e);
            int s = __builtin_nontemporal_load(src + e);
            if ((t >> rsh) == r) atomicAdd(&deg2[t], 1);
            if ((s >> rsh) == r) atomicAdd(&deg2[n_nodes + s], 1);
        }
    }
}

// ---------------- 3-kernel exclusive prefix scan over deg2[0..n2) ----------------

__global__ __launch_bounds__(256)
void scan_pass1(const int* __restrict__ deg, int* __restrict__ bs, int n) {
    __shared__ int sh[256];
    int t = threadIdx.x;
    int base = blockIdx.x * 2048 + t * 8;
    int s = 0;
#pragma unroll
    for (int j = 0; j < 8; j++) { int idx = base + j; if (idx < n) s += deg[idx]; }
    sh[t] = s; __syncthreads();
    for (int st = 128; st > 0; st >>= 1) { if (t < st) sh[t] += sh[t + st]; __syncthreads(); }
    if (t == 0) bs[blockIdx.x] = sh[0];
}

__global__ void scan_pass2(int* __restrict__ bs, int nb) {
    __shared__ int sh[1024];
    int t = threadIdx.x;
    int v = (t < nb) ? bs[t] : 0;
    sh[t] = v; __syncthreads();
    for (int off = 1; off < 1024; off <<= 1) {
        int u = (t >= off) ? sh[t - off] : 0; __syncthreads();
        sh[t] += u; __syncthreads();
    }
    if (t < nb) bs[t] = sh[t] - v;   // exclusive
}

__global__ __launch_bounds__(256)
void scan_pass3(const int* __restrict__ deg, const int* __restrict__ bs,
                int* __restrict__ off, int n) {
    __shared__ int sh[256];
    int t = threadIdx.x;
    int base = blockIdx.x * 2048 + t * 8;
    int v[8]; int s = 0;
#pragma unroll
    for (int j = 0; j < 8; j++) { int idx = base + j; v[j] = (idx < n) ? deg[idx] : 0; s += v[j]; }
    sh[t] = s; __syncthreads();
    for (int st = 1; st < 256; st <<= 1) {
        int u = (t >= st) ? sh[t - st] : 0; __syncthreads();
        sh[t] += u; __syncthreads();
    }
    int acc = bs[blockIdx.x] + sh[t] - s;
#pragma unroll
    for (int j = 0; j < 8; j++) { int idx = base + j; if (idx < n) off[idx] = acc; acc += v[j]; }
}

// ---------------- scatter edges, range-split, nt edge reads ----------------

__global__ __launch_bounds__(256)
void scatter_range_kernel(const int* __restrict__ src, const int* __restrict__ tgt,
                          int* __restrict__ cur2, int* __restrict__ nbr,
                          int n_nodes, int n_edges, int rsh) {
    int r = blockIdx.x & (NRANGE - 1);
    int chunk = blockIdx.x >> 3;
    int base = chunk * 2048;
#pragma unroll
    for (int j = 0; j < 8; j++) {
        int e = base + j * 256 + threadIdx.x;
        if (e < n_edges) {
            int t = __builtin_nontemporal_load(tgt + e);
            int s = __builtin_nontemporal_load(src + e);
            if ((t >> rsh) == r) { int p = atomicAdd(&cur2[t], 1);           nbr[p] = s; }
            if ((s >> rsh) == r) { int q = atomicAdd(&cur2[n_nodes + s], 1); nbr[q] = t; }
        }
    }
}

// ---------------- init: x (fp32) + xg (bf16 mirror), norms ----------------

__global__ __launch_bounds__(256)
void init_kernel(const int* __restrict__ nodes, const float* __restrict__ emb,
                 const int* __restrict__ deg2,
                 float* __restrict__ x, unsigned short* __restrict__ xg,
                 float* __restrict__ norm, float* __restrict__ norm_t, int n_nodes) {
    int gid = blockIdx.x * blockDim.x + threadIdx.x;
    int i = gid >> 5, c = gid & 31;
    if (i >= n_nodes) return;
    float v = emb[nodes[i] * CHANNELS + c];
    x[gid] = v;
    xg[gid] = (unsigned short)f2bf_rne(v);
    if (c == 0) {
        norm[i]   = 1.0f / (1.0f + (float)deg2[i]);
        norm_t[i] = 1.0f / (1.0f + (float)deg2[n_nodes + i]);
    }
}

// ---------------- counts via binary search over sorted batch ----------------

__global__ void counts_kernel(const int* __restrict__ batch, float* __restrict__ counts,
                              int n_nodes, int n_graphs) {
    int b = blockIdx.x * blockDim.x + threadIdx.x;
    if (b >= n_graphs) return;
    int lo = 0, hi = n_nodes;
    while (lo < hi) { int mid = (lo + hi) >> 1; if (batch[mid] < b) lo = mid + 1; else hi = mid; }
    int s = lo;
    lo = 0; hi = n_nodes;
    while (lo < hi) { int mid = (lo + hi) >> 1; if (batch[mid] < b + 1) lo = mid + 1; else hi = mid; }
    counts[b] = (float)(lo - s);
}

// ---------------- fused layer: bf16 gather + split-bf16 MFMA, in-place fp32 x ----
// Gathers read the bf16 mirror xgin (64 B/row). fp32 residual x is updated in
// place: only a node's own block touches its row. xgout (next layer's mirror)
// written in epilogue.

__global__ __launch_bounds__(256)
void layer_mfma(const int* __restrict__ off2, const int* __restrict__ nbr,
                const float* __restrict__ wbase,
                const float* __restrict__ norm, const float* __restrict__ norm_t,
                float* __restrict__ x,
                const unsigned short* __restrict__ xgin,
                unsigned short* __restrict__ xgout,
                int n_nodes, int n_edges) {
    __shared__ short A1h[64][32], A1l[64][32], A2h[64][32], A2l[64][32];
    __shared__ short W0h[32][32], W0l[32][32], W1h[32][32], W1l[32][32]; // [n][k]

    int tid = threadIdx.x;
    for (int idx = tid; idx < CHANNELS * CHANNELS; idx += 256) {
        int k = idx >> 5, n = idx & 31;
        float w0 = wbase[idx];
        float w1 = wbase[CHANNELS * CHANNELS + idx];
        short h0 = f2bf_rne(w0); W0h[n][k] = h0; W0l[n][k] = f2bf_rne(w0 - bf2f(h0));
        short h1 = f2bf_rne(w1); W1h[n][k] = h1; W1l[n][k] = f2bf_rne(w1 - bf2f(h1));
    }

    int c = tid & 31, sub = tid >> 5;
    int nodeblock = blockIdx.x * 64;

    for (int pass = 0; pass < 8; pass++) {
        int local = pass * 8 + sub;
        int i = nodeblock + local;
        if (i < n_nodes) {
            float xv = x[i * CHANNELS + c];

            int b_in  = off2[i];
            int e_in  = (i + 1 < n_nodes) ? off2[i + 1] : n_edges;
            int b_out = off2[n_nodes + i];
            int e_out = (i + 1 < n_nodes) ? off2[n_nodes + i + 1] : 2 * n_edges;

            float a1 = 0.f;
            {
                int deg = e_in - b_in;
                int nbl = (c < deg) ? nbr[b_in + c] : 0;
                int m = deg < 32 ? deg : 32;
                for (int j = 0; j < m; j += 4) {
                    int n0 = __shfl(nbl, j, 32);
                    int n1 = __shfl(nbl, j + 1, 32);
                    int n2 = __shfl(nbl, j + 2, 32);
                    int n3 = __shfl(nbl, j + 3, 32);
                    n1 = (j + 1 < m) ? n1 : i;
                    n2 = (j + 2 < m) ? n2 : i;
                    n3 = (j + 3 < m) ? n3 : i;
                    float v0 = bfu2f(xgin[n0 * CHANNELS + c]);
                    float v1 = bfu2f(xgin[n1 * CHANNELS + c]);
                    float v2 = bfu2f(xgin[n2 * CHANNELS + c]);
                    float v3 = bfu2f(xgin[n3 * CHANNELS + c]);
                    a1 += v0;
                    a1 += (j + 1 < m) ? v1 : 0.f;
                    a1 += (j + 2 < m) ? v2 : 0.f;
                    a1 += (j + 3 < m) ? v3 : 0.f;
                }
                for (int e = b_in + 32; e < e_in; e++) a1 += bfu2f(xgin[nbr[e] * CHANNELS + c]);
            }
            float a2 = 0.f;
            {
                int deg = e_out - b_out;
                int nbl = (c < deg) ? nbr[b_out + c] : 0;
                int m = deg < 32 ? deg : 32;
                for (int j = 0; j < m; j += 4) {
                    int n0 = __shfl(nbl, j, 32);
                    int n1 = __shfl(nbl, j + 1, 32);
                    int n2 = __shfl(nbl, j + 2, 32);
                    int n3 = __shfl(nbl, j + 3, 32);
                    n1 = (j + 1 < m) ? n1 : i;
                    n2 = (j + 2 < m) ? n2 : i;
                    n3 = (j + 3 < m) ? n3 : i;
                    float v0 = bfu2f(xgin[n0 * CHANNELS + c]);
                    float v1 = bfu2f(xgin[n1 * CHANNELS + c]);
                    float v2 = bfu2f(xgin[n2 * CHANNELS + c]);
                    float v3 = bfu2f(xgin[n3 * CHANNELS + c]);
                    a2 += v0;
                    a2 += (j + 1 < m) ? v1 : 0.f;
                    a2 += (j + 2 < m) ? v2 : 0.f;
                    a2 += (j + 3 < m) ? v3 : 0.f;
                }
                for (int e = b_out + 32; e < e_out; e++) a2 += bfu2f(xgin[nbr[e] * CHANNELS + c]);
            }

            a1 = norm[i]   * (xv + a1);
            a2 = norm_t[i] * (xv + a2);
            short h1s = f2bf_rne(a1);
            A1h[local][c] = h1s; A1l[local][c] = f2bf_rne(a1 - bf2f(h1s));
            short h2s = f2bf_rne(a2);
            A2h[local][c] = h2s; A2l[local][c] = f2bf_rne(a2 - bf2f(h2s));
        }
    }
    __syncthreads();

    int wv = tid >> 6, lane = tid & 63;
    int m = lane & 15, quad = lane >> 4;
    int row0 = wv * 16;

    short8 a1h = *(const short8*)&A1h[row0 + m][quad * 8];
    short8 a1l = *(const short8*)&A1l[row0 + m][quad * 8];
    short8 a2h = *(const short8*)&A2h[row0 + m][quad * 8];
    short8 a2l = *(const short8*)&A2l[row0 + m][quad * 8];

    float4v dd[4];
#pragma unroll
    for (int h = 0; h < 2; h++) {
        int n0 = h * 16 + m;
        short8 b0h = *(const short8*)&W0h[n0][quad * 8];
        short8 b0l = *(const short8*)&W0l[n0][quad * 8];
        short8 b1h = *(const short8*)&W1h[n0][quad * 8];
        short8 b1l = *(const short8*)&W1l[n0][quad * 8];
        float4v d1 = {0.f, 0.f, 0.f, 0.f};
        d1 = __builtin_amdgcn_mfma_f32_16x16x32_bf16(a1h, b0h, d1, 0, 0, 0);
        d1 = __builtin_amdgcn_mfma_f32_16x16x32_bf16(a1l, b0h, d1, 0, 0, 0);
        d1 = __builtin_amdgcn_mfma_f32_16x16x32_bf16(a1h, b0l, d1, 0, 0, 0);
        float4v d2 = {0.f, 0.f, 0.f, 0.f};
        d2 = __builtin_amdgcn_mfma_f32_16x16x32_bf16(a2h, b1h, d2, 0, 0, 0);
        d2 = __builtin_amdgcn_mfma_f32_16x16x32_bf16(a2l, b1h, d2, 0, 0, 0);
        d2 = __builtin_amdgcn_mfma_f32_16x16x32_bf16(a2h, b1l, d2, 0, 0, 0);
        dd[h * 2] = d1; dd[h * 2 + 1] = d2;
    }

#pragma unroll
    for (int h = 0; h < 2; h++) {
        float4v d1 = dd[h * 2], d2 = dd[h * 2 + 1];
#pragma unroll
        for (int r = 0; r < 4; r++) {
            int local = row0 + quad * 4 + r;
            int node = nodeblock + local;
            if (node < n_nodes) {
                int col = h * 16 + m;
                float v = x[node * CHANNELS + col] + fmaxf(d1[r], 0.f) + fmaxf(d2[r], 0.f);
                x[node * CHANNELS + col] = v;
                xgout[node * CHANNELS + col] = (unsigned short)f2bf_rne(v);
            }
        }
    }
}

// ---------------- pooling: run-length accumulate over sorted batch ----------------

#define POOL_CHUNK 2048

__global__ __launch_bounds__(256)
void pool_kernel(const int* __restrict__ batch, const float* __restrict__ x,
                 float* __restrict__ g, int n_nodes) {
    int c = threadIdx.x & 31;
    int r = threadIdx.x >> 5;
    int base = blockIdx.x * POOL_CHUNK;
    float acc = 0.f;
    int cur = -1;
    for (int it = 0; it < POOL_CHUNK / 8; it++) {
        int node = base + it * 8 + r;
        if (node >= n_nodes) break;
        int b = batch[node];
        if (b != cur) {
            if (cur >= 0) atomicAdd(&g[cur * CHANNELS + c], acc);
            acc = 0.f;
            cur = b;
        }
        acc += x[node * CHANNELS + c];
    }
    if (cur >= 0) atomicAdd(&g[cur * CHANNELS + c], acc);
}

// ---------------- MLP head: one block per graph ----------------

__global__ __launch_bounds__(256)
void mlp_kernel(const float* __restrict__ g, const float* __restrict__ counts,
                const float* __restrict__ hidden_w, const float* __restrict__ hidden_b,
                const float* __restrict__ out_w, float* __restrict__ out) {
    __shared__ float grow[CHANNELS];
    __shared__ float red[256];
    int graph = blockIdx.x;
    int tid = threadIdx.x;
    if (tid < CHANNELS) grow[tid] = g[graph * CHANNELS + tid] / counts[graph];
    __syncthreads();
    float partial = 0.f;
    for (int q = 0; q < HIDDEN / 256; q++) {
        int j = q * 256 + tid;
        float h = hidden_b[j];
#pragma unroll
        for (int k = 0; k < CHANNELS; k++) h += grow[k] * hidden_w[k * HIDDEN + j];
        partial += fmaxf(h, 0.f) * out_w[j];
    }
    red[tid] = partial;
    __syncthreads();
    for (int s = 128; s > 0; s >>= 1) {
        if (tid < s) red[tid] += red[tid + s];
        __syncthreads();
    }
    if (tid == 0) out[graph] = red[0];
}

// ---------------- launch ----------------

extern "C" void kernel_launch(void* const* d_in, const int* in_sizes, int n_in,
                              void* d_out, int out_size, void* d_ws, size_t ws_size,
                              hipStream_t stream) {
    const int*   nodes    = (const int*)d_in[0];
    const int*   sources  = (const int*)d_in[1];
    const int*   targets  = (const int*)d_in[2];
    const int*   batch    = (const int*)d_in[3];
    const float* emb      = (const float*)d_in[4];
    const float* conv_w   = (const float*)d_in[5];
    const float* hidden_w = (const float*)d_in[6];
    const float* hidden_b = (const float*)d_in[7];
    const float* out_w    = (const float*)d_in[8];
    float* out = (float*)d_out;

    const int n_nodes  = in_sizes[0];
    const int n_edges  = in_sizes[1];
    const int n_graphs = out_size;
    const int n2 = 2 * n_nodes;

    int rsh = 0;
    while (((n_nodes - 1) >> rsh) >= NRANGE) rsh++;

    char* ws = (char*)d_ws;
    float*          x      = (float*)ws;          ws += (size_t)n_nodes * CHANNELS * 4;
    unsigned short* xg0    = (unsigned short*)ws; ws += (size_t)n_nodes * CHANNELS * 2;
    unsigned short* xg1    = (unsigned short*)ws; ws += (size_t)n_nodes * CHANNELS * 2;
    float* norm   = (float*)ws; ws += (size_t)n_nodes * 4;
    float* norm_t = (float*)ws; ws += (size_t)n_nodes * 4;
    int*   deg2   = (int*)ws;   ws += (size_t)n2 * 4;
    int*   off2   = (int*)ws;   ws += (size_t)n2 * 4;
    int*   cur2   = (int*)ws;   ws += (size_t)n2 * 4;
    int*   nbr    = (int*)ws;   ws += (size_t)2 * n_edges * 4;
    int*   bsums  = (int*)ws;   ws += 4096;
    float* g      = (float*)ws; ws += (size_t)n_graphs * CHANNELS * 4;
    float* counts = (float*)ws; ws += (size_t)n_graphs * 4;

    hipMemsetAsync(deg2, 0, (size_t)n2 * 4, stream);
    hipMemsetAsync(g, 0, (size_t)n_graphs * CHANNELS * 4, stream);

    int echunks = (n_edges + 2047) / 2048;

    // 1. degrees (range-split, XCD-affine, nt edge reads)
    deg_range_kernel<<<echunks * NRANGE, 256, 0, stream>>>(sources, targets, deg2,
                                                           n_nodes, n_edges, rsh);

    // 2. exclusive scan deg2 -> off2
    int nblk = (n2 + 2047) / 2048;
    scan_pass1<<<nblk, 256, 0, stream>>>(deg2, bsums, n2);
    scan_pass2<<<1, 1024, 0, stream>>>(bsums, nblk);
    scan_pass3<<<nblk, 256, 0, stream>>>(deg2, bsums, off2, n2);

    // 3. cursors = offsets copy, then scatter neighbor ids (range-split, nt reads)
    hipMemcpyAsync(cur2, off2, (size_t)n2 * 4, hipMemcpyDeviceToDevice, stream);
    scatter_range_kernel<<<echunks * NRANGE, 256, 0, stream>>>(sources, targets, cur2, nbr,
                                                               n_nodes, n_edges, rsh);

    // 4. init features + norms; counts via binary search
    int node_thr = n_nodes * CHANNELS;
    init_kernel<<<(node_thr + 255) / 256, 256, 0, stream>>>(nodes, emb, deg2, x, xg0,
                                                            norm, norm_t, n_nodes);
    counts_kernel<<<(n_graphs + 255) / 256, 256, 0, stream>>>(batch, counts, n_nodes, n_graphs);

    // 5. layers: fp32 x in place, bf16 mirror ping-pongs
    unsigned short* xgin = xg0; unsigned short* xgout = xg1;
    int lblocks = (n_nodes + 63) / 64;
    for (int l = 0; l < LAYERS; l++) {
        const float* wbase = conv_w + (size_t)l * 2 * CHANNELS * CHANNELS;
        layer_mfma<<<lblocks, 256, 0, stream>>>(off2, nbr, wbase, norm, norm_t,
                                                x, xgin, xgout, n_nodes, n_edges);
        unsigned short* tmp = xgin; xgin = xgout; xgout = tmp;
    }

    // 6. pool + head
    int pool_blocks = (n_nodes + POOL_CHUNK - 1) / POOL_CHUNK;
    pool_kernel<<<pool_blocks, 256, 0, stream>>>(batch, x, g, n_nodes);
    mlp_kernel<<<n_graphs, 256, 0, stream>>>(g, counts, hidden_w, hidden_b, out_w, out);
}